// Round 6
// baseline (664.920 us; speedup 1.0000x reference)
//
#include <hip/hip_runtime.h>
#include <hip/hip_bf16.h>
#include <math.h>

// Problem constants
#define BB 2
#define SS 2048
#define EE 1024
#define HH 16
#define HD 64
#define FFF 4096
#define MROWS (BB * SS)        // 4096
#define EPS_F 1.1920929e-7f

typedef __hip_bfloat16 bf16;
typedef __attribute__((ext_vector_type(8))) short short8;
typedef __attribute__((ext_vector_type(4))) short short4v;
typedef __attribute__((ext_vector_type(4))) float floatx4;

typedef const __attribute__((address_space(1))) void* gas_t;
typedef __attribute__((address_space(3))) void* las_t;

// ---------------------------------------------------------------------------
// RMSNorm: fp32 in, bf16 out
// ---------------------------------------------------------------------------
__global__ __launch_bounds__(256) void rmsnorm_kernel(const float* __restrict__ x,
                                                      const float* __restrict__ g,
                                                      bf16* __restrict__ out,
                                                      int cols) {
    int row = blockIdx.x;
    const float* xr = x + (size_t)row * cols;
    float ss = 0.0f;
    for (int c = threadIdx.x; c < cols; c += 256) {
        float v = xr[c];
        ss += v * v;
    }
    for (int off = 32; off > 0; off >>= 1) ss += __shfl_xor(ss, off, 64);
    __shared__ float red[4];
    int wave = threadIdx.x >> 6;
    if ((threadIdx.x & 63) == 0) red[wave] = ss;
    __syncthreads();
    float tot = red[0] + red[1] + red[2] + red[3];
    float rs = rsqrtf(tot / (float)cols + EPS_F);
    bf16* orow = out + (size_t)row * cols;
    for (int c = threadIdx.x; c < cols; c += 256) {
        orow[c] = __float2bfloat16(xr[c] * rs * g[c]);
    }
}

// ---------------------------------------------------------------------------
// Cast + transpose: W (K x N, fp32) -> Wt (N x K, bf16). 32x32 LDS tiles.
// ---------------------------------------------------------------------------
__global__ __launch_bounds__(256) void transpose_cast_kernel(const float* __restrict__ W,
                                                             bf16* __restrict__ Wt,
                                                             int K, int N) {
    __shared__ float t[32][33];
    int n0 = blockIdx.x * 32, k0 = blockIdx.y * 32;
    int tx = threadIdx.x & 31, ty = threadIdx.x >> 5;   // ty 0..7
#pragma unroll
    for (int i = 0; i < 4; ++i) {
        int kk = ty + i * 8;
        t[kk][tx] = W[(size_t)(k0 + kk) * N + n0 + tx];
    }
    __syncthreads();
#pragma unroll
    for (int i = 0; i < 4; ++i) {
        int nn = ty + i * 8;
        Wt[(size_t)(n0 + nn) * K + k0 + tx] = __float2bfloat16(t[tx][nn]);
    }
}

// pack [bk | bv] -> bkv (128 floats)
__global__ void pack_bkv_kernel(const float* __restrict__ bk, const float* __restrict__ bv,
                                float* __restrict__ bkv) {
    int t = threadIdx.x;
    bkv[t] = (t < 64) ? bk[t] : bv[t - 64];
}

// ---------------------------------------------------------------------------
// bf16 MFMA GEMM (m97 structure): C[M,N] = A[M,K] @ Bt[N,K]^T + bias.
// 128x128 tile, BK=64, global_load_lds width=16 staging, unpadded LDS.
// mode: 0 none; 1 += fp32 aux; 2 exact GELU; 3 *= bf16 aux.  obf: bf16 out.
// ---------------------------------------------------------------------------
#define GM 128
#define GN 128
#define GK 64

__global__ __launch_bounds__(256) void gemm_bf16_kernel(
        const bf16* __restrict__ A, const bf16* __restrict__ Bt,
        const float* __restrict__ bias, const void* __restrict__ aux,
        void* __restrict__ C, int M, int N, int K, int mode, int obf) {
    __shared__ short As[GM * GK];
    __shared__ short Bs[GN * GK];
    int tid = threadIdx.x;
    int wave = tid >> 6, lane = tid & 63;
    int wm = (wave >> 1) * 64, wn = (wave & 1) * 64;
    int row0 = blockIdx.y * GM, col0 = blockIdx.x * GN;
    int lr = lane & 15, lq = lane >> 4;

    // staging geometry: wave w stages rows [w*32, w*32+32), 4 calls of 8 rows;
    // lane l covers row +l/8, 16B chunk l%8 (LDS dst = base + l*16, matches row-major)
    int srow = wave * 32 + (lane >> 3);
    int scol = (lane & 7) * 8;
    const bf16* Abase = A + (size_t)(row0 + srow) * K + scol;
    const bf16* Bbase = Bt + (size_t)(col0 + srow) * K + scol;

    floatx4 acc[4][4];
#pragma unroll
    for (int mi = 0; mi < 4; ++mi)
#pragma unroll
        for (int ni = 0; ni < 4; ++ni)
            acc[mi][ni] = (floatx4){0.f, 0.f, 0.f, 0.f};

    for (int k0 = 0; k0 < K; k0 += GK) {
        __syncthreads();
#pragma unroll
        for (int c = 0; c < 4; ++c) {
            __builtin_amdgcn_global_load_lds(
                (gas_t)(Abase + (size_t)(c * 8) * K + k0),
                (las_t)&As[(wave * 32 + c * 8) * GK], 16, 0, 0);
            __builtin_amdgcn_global_load_lds(
                (gas_t)(Bbase + (size_t)(c * 8) * K + k0),
                (las_t)&Bs[(wave * 32 + c * 8) * GK], 16, 0, 0);
        }
        __syncthreads();
#pragma unroll
        for (int ks = 0; ks < GK; ks += 32) {
            short8 af[4], bfr[4];
#pragma unroll
            for (int mi = 0; mi < 4; ++mi)
                af[mi] = *(const short8*)&As[(wm + mi * 16 + lr) * GK + ks + lq * 8];
#pragma unroll
            for (int ni = 0; ni < 4; ++ni)
                bfr[ni] = *(const short8*)&Bs[(wn + ni * 16 + lr) * GK + ks + lq * 8];
#pragma unroll
            for (int mi = 0; mi < 4; ++mi)
#pragma unroll
                for (int ni = 0; ni < 4; ++ni)
                    acc[mi][ni] = __builtin_amdgcn_mfma_f32_16x16x32_bf16(
                        af[mi], bfr[ni], acc[mi][ni], 0, 0, 0);
        }
    }

#pragma unroll
    for (int mi = 0; mi < 4; ++mi) {
#pragma unroll
        for (int ni = 0; ni < 4; ++ni) {
            int gc = col0 + wn + ni * 16 + lr;
            float bv = bias[gc];
#pragma unroll
            for (int r = 0; r < 4; ++r) {
                int gr = row0 + wm + mi * 16 + lq * 4 + r;
                size_t idx = (size_t)gr * N + gc;
                float c = acc[mi][ni][r] + bv;
                if (mode == 1)      c += ((const float*)aux)[idx];
                else if (mode == 2) c = 0.5f * c * (1.0f + erff(c * 0.70710678118654752f));
                else if (mode == 3) c *= (float)((const bf16*)aux)[idx];
                if (obf) ((bf16*)C)[idx] = __float2bfloat16(c);
                else     ((float*)C)[idx] = c;
            }
        }
    }
}

// ---------------------------------------------------------------------------
// RoPE on bf16 q, in place, 1/sqrt(HD) folded. pos = row % SS.
// ---------------------------------------------------------------------------
__global__ __launch_bounds__(256) void rope_q_kernel(bf16* __restrict__ t, int total) {
    int idx = blockIdx.x * 256 + threadIdx.x;
    if (idx >= total) return;
    int i = idx & 31;
    int h = (idx >> 5) % HH;
    int row = idx / (32 * HH);
    int s = row & (SS - 1);
    float inv = powf(10000.0f, -(float)i / 32.0f);
    float ang = (float)s * inv;
    float c = cosf(ang), sn = sinf(ang);
    size_t base = (size_t)row * (HH * HD) + h * 64 + i;
    float t1 = (float)t[base];
    float t2 = (float)t[base + 32];
    t[base]      = __float2bfloat16((t1 * c - t2 * sn) * 0.125f);
    t[base + 32] = __float2bfloat16((t1 * sn + t2 * c) * 0.125f);
}

// ---------------------------------------------------------------------------
// prep_kv: kv fp32 (MROWS,128) -> kbf bf16 (MROWS,64) roped,
//          vtb bf16 (BB,64,SS) = V transposed per batch.
// ---------------------------------------------------------------------------
__global__ __launch_bounds__(256) void prep_kv_kernel(const float* __restrict__ kv,
                                                      bf16* __restrict__ kbf,
                                                      bf16* __restrict__ vtb) {
    __shared__ float vt[64][65];
    int s0 = blockIdx.x * 64;
    int b  = blockIdx.y;
    int tid = threadIdx.x;

    for (int i = tid; i < 2048; i += 256) {
        int sl = i >> 5, ii = i & 31;
        int s = s0 + sl;
        size_t base = ((size_t)(b * SS + s)) * 128;
        float k1 = kv[base + ii], k2 = kv[base + ii + 32];
        float inv = powf(10000.0f, -(float)ii / 32.0f);
        float ang = (float)s * inv;
        float c = cosf(ang), sn = sinf(ang);
        size_t ob = ((size_t)(b * SS + s)) * 64;
        kbf[ob + ii]      = __float2bfloat16(k1 * c - k2 * sn);
        kbf[ob + ii + 32] = __float2bfloat16(k1 * sn + k2 * c);
    }

    for (int i = tid; i < 4096; i += 256) {
        int s = i >> 6, d = i & 63;
        vt[d][s] = kv[((size_t)(b * SS + s0 + s)) * 128 + 64 + d];
    }
    __syncthreads();
    for (int i = tid; i < 4096; i += 256) {
        int d = i >> 6, sl = i & 63;
        vtb[((size_t)(b * 64 + d)) * SS + s0 + sl] = __float2bfloat16(vt[d][sl]);
    }
}

// ---------------------------------------------------------------------------
// MFMA flash attention v3: barrier-free, load-balanced.
// grid (16, HH, BB); block = 4 waves. Block x handles q-tiles x and 31-x
// (uniform 33 key-tiles). K/V fragments read directly from global (L1/L2-
// resident, 4-wave reuse). Only LDS: wave-private P round-trip (stride 68:
// b16 writes conflict-free, b64 reads 8B-aligned).
// ---------------------------------------------------------------------------
#define PST 68

__global__ __launch_bounds__(256) void attn_mfma_kernel(
        const bf16* __restrict__ q, const bf16* __restrict__ kb,
        const bf16* __restrict__ vt, bf16* __restrict__ o) {
    __shared__ short Ps[4][16 * PST];

    int h = blockIdx.y, b = blockIdx.z;
    int tid = threadIdx.x, w = tid >> 6, lane = tid & 63;
    int lr = lane & 15, quad = lane >> 4;

    const bf16* kbB = kb + (size_t)b * SS * 64;
    const bf16* vtB = vt + (size_t)b * 64 * SS;

    for (int pass = 0; pass < 2; ++pass) {
        int qt = (pass == 0) ? (int)blockIdx.x : (SS / 64 - 1 - (int)blockIdx.x);
        int q0 = qt * 64;

        const bf16* qrow = q + ((size_t)(b * SS + q0 + w * 16 + lr)) * (HH * HD) + h * HD;
        short8 qf0 = *(const short8*)(qrow + quad * 8);
        short8 qf1 = *(const short8*)(qrow + 32 + quad * 8);

        floatx4 O[4];
#pragma unroll
        for (int ni = 0; ni < 4; ++ni) O[ni] = (floatx4){0.f, 0.f, 0.f, 0.f};
        float mrow[4] = {-3.0e38f, -3.0e38f, -3.0e38f, -3.0e38f};
        float lrow[4] = {0.f, 0.f, 0.f, 0.f};

        for (int t = 0; t <= qt; ++t) {
            int j0 = t * 64;

            // S = Q @ K^T : K fragments direct from global
            floatx4 S[4];
#pragma unroll
            for (int ni = 0; ni < 4; ++ni) S[ni] = (floatx4){0.f, 0.f, 0.f, 0.f};
#pragma unroll
            for (int ni = 0; ni < 4; ++ni) {
                const bf16* kr = kbB + (size_t)(j0 + ni * 16 + lr) * 64 + quad * 8;
                short8 b0 = *(const short8*)(kr);
                short8 b1 = *(const short8*)(kr + 32);
                S[ni] = __builtin_amdgcn_mfma_f32_16x16x32_bf16(qf0, b0, S[ni], 0, 0, 0);
                S[ni] = __builtin_amdgcn_mfma_f32_16x16x32_bf16(qf1, b1, S[ni], 0, 0, 0);
            }

            // causal mask on diagonal tile
            if (t == qt) {
                int rowg = q0 + w * 16 + quad * 4;
#pragma unroll
                for (int ni = 0; ni < 4; ++ni) {
                    int colg = j0 + ni * 16 + lr;
#pragma unroll
                    for (int r = 0; r < 4; ++r)
                        if (colg > rowg + r) S[ni][r] = -3.0e38f;
                }
            }

            // online softmax; rows = quad*4+r; reduce over the quad's 16 lanes
            float alpha[4];
#pragma unroll
            for (int r = 0; r < 4; ++r) {
                float mx = fmaxf(fmaxf(S[0][r], S[1][r]), fmaxf(S[2][r], S[3][r]));
                for (int off = 8; off > 0; off >>= 1) mx = fmaxf(mx, __shfl_xor(mx, off, 64));
                float mn = fmaxf(mrow[r], mx);
                alpha[r] = __expf(mrow[r] - mn);
                mrow[r] = mn;
                float psum = 0.f;
#pragma unroll
                for (int ni = 0; ni < 4; ++ni) {
                    float p = __expf(S[ni][r] - mn);
                    S[ni][r] = p;
                    psum += p;
                }
                for (int off = 8; off > 0; off >>= 1) psum += __shfl_xor(psum, off, 64);
                lrow[r] = lrow[r] * alpha[r] + psum;
            }

            // rescale O; pack P (bf16) to wave-private LDS in C-layout
#pragma unroll
            for (int ni = 0; ni < 4; ++ni) {
#pragma unroll
                for (int r = 0; r < 4; ++r) {
                    O[ni][r] *= alpha[r];
                    bf16 pb = __float2bfloat16(S[ni][r]);
                    Ps[w][(quad * 4 + r) * PST + ni * 16 + lr] = *(short*)&pb;
                }
            }
            // read P back as A-fragments (b64 pairs; same-wave ordering)
            short4v a0 = *(const short4v*)&Ps[w][lr * PST + quad * 8];
            short4v a1 = *(const short4v*)&Ps[w][lr * PST + quad * 8 + 4];
            short4v a2 = *(const short4v*)&Ps[w][lr * PST + 32 + quad * 8];
            short4v a3 = *(const short4v*)&Ps[w][lr * PST + 32 + quad * 8 + 4];
            short8 p0 = __builtin_shufflevector(a0, a1, 0, 1, 2, 3, 4, 5, 6, 7);
            short8 p1 = __builtin_shufflevector(a2, a3, 0, 1, 2, 3, 4, 5, 6, 7);

            // O += P @ V : V fragments direct from global (vt: d-major)
#pragma unroll
            for (int ni = 0; ni < 4; ++ni) {
                const bf16* vr = vtB + (size_t)(ni * 16 + lr) * SS + j0 + quad * 8;
                short8 v0 = *(const short8*)(vr);
                short8 v1 = *(const short8*)(vr + 32);
                O[ni] = __builtin_amdgcn_mfma_f32_16x16x32_bf16(p0, v0, O[ni], 0, 0, 0);
                O[ni] = __builtin_amdgcn_mfma_f32_16x16x32_bf16(p1, v1, O[ni], 0, 0, 0);
            }
        }

        // epilogue for this pass
#pragma unroll
        for (int ni = 0; ni < 4; ++ni) {
            int gc = h * 64 + ni * 16 + lr;
#pragma unroll
            for (int r = 0; r < 4; ++r) {
                int gr = b * SS + q0 + w * 16 + quad * 4 + r;
                o[(size_t)gr * (HH * HD) + gc] = __float2bfloat16(O[ni][r] / lrow[r]);
            }
        }
    }
}

// ---------------------------------------------------------------------------
// Launch. Workspace (byte offsets, ~87 MB):
//   qbf @0 (8 MB bf16, dead after attn; wgT reuses @0)
//   wuT @8M | x2 @16M (fp32, alive to end) | h1b/h2b @32M | kv @40M
//   ao @42M (dead after wo GEMM; wdT reuses) | gg @50M (kbf/vtb live there
//   pre-FFN) | wqT @82M | wkvT @84M | bkv @84.5M | woT @85M
// ---------------------------------------------------------------------------
#define MB (1024ull * 1024ull)

extern "C" void kernel_launch(void* const* d_in, const int* in_sizes, int n_in,
                              void* d_out, int out_size, void* d_ws, size_t ws_size,
                              hipStream_t stream) {
    const float* x  = (const float*)d_in[0];
    const float* wq = (const float*)d_in[1];
    const float* bq = (const float*)d_in[2];
    const float* wk = (const float*)d_in[3];
    const float* bk = (const float*)d_in[4];
    const float* wv = (const float*)d_in[5];
    const float* bv = (const float*)d_in[6];
    const float* wo = (const float*)d_in[7];
    const float* bo = (const float*)d_in[8];
    const float* wg = (const float*)d_in[9];
    const float* bg = (const float*)d_in[10];
    const float* wu = (const float*)d_in[11];
    const float* bu = (const float*)d_in[12];
    const float* wd = (const float*)d_in[13];
    const float* bd = (const float*)d_in[14];
    const float* g1 = (const float*)d_in[15];
    const float* g2 = (const float*)d_in[16];
    float* out = (float*)d_out;

    char* ws = (char*)d_ws;
    bf16*  qbf  = (bf16*)(ws);
    bf16*  wuT  = (bf16*)(ws + 8 * MB);
    float* x2   = (float*)(ws + 16 * MB);
    bf16*  h1b  = (bf16*)(ws + 32 * MB);
    float* kv   = (float*)(ws + 40 * MB);
    bf16*  ao   = (bf16*)(ws + 42 * MB);
    bf16*  gg   = (bf16*)(ws + 50 * MB);
    bf16*  kbf  = (bf16*)(ws + 50 * MB);             // over gg head (dead by FFN)
    bf16*  vtb  = (bf16*)(ws + 50 * MB + 512 * 1024);
    bf16*  wqT  = (bf16*)(ws + 82 * MB);
    bf16*  wkvT = (bf16*)(ws + 84 * MB);
    float* bkv  = (float*)(ws + 84 * MB + 512 * 1024);
    bf16*  woT  = (bf16*)(ws + 85 * MB);
    bf16*  wgT  = (bf16*)(ws);                        // over qbf (dead after attn)
    bf16*  wdT  = (bf16*)(ws + 42 * MB);              // over ao (dead after wo GEMM)
    bf16*  h2b  = h1b;

    // 1. h1 = rmsnorm(x, g1)
    rmsnorm_kernel<<<MROWS, 256, 0, stream>>>(x, g1, h1b, EE);

    // 2. weight transposes for attention block
    transpose_cast_kernel<<<dim3(EE / 32, EE / 32), 256, 0, stream>>>(wq, wqT, EE, EE);
    transpose_cast_kernel<<<dim3(HD / 32, EE / 32), 256, 0, stream>>>(wk, wkvT, EE, HD);
    transpose_cast_kernel<<<dim3(HD / 32, EE / 32), 256, 0, stream>>>(wv, wkvT + 64 * EE, EE, HD);
    pack_bkv_kernel<<<1, 128, 0, stream>>>(bk, bv, bkv);
    transpose_cast_kernel<<<dim3(EE / 32, EE / 32), 256, 0, stream>>>(wo, woT, EE, EE);

    // 3. qbf = h1 @ wq + bq  [bf16]
    gemm_bf16_kernel<<<dim3(EE / GN, MROWS / GM), 256, 0, stream>>>(
        h1b, wqT, bq, nullptr, qbf, MROWS, EE, EE, 0, 1);
    // 4. kv = h1 @ [wk|wv] + [bk|bv]  [fp32, N=128]
    gemm_bf16_kernel<<<dim3(1, MROWS / GM), 256, 0, stream>>>(
        h1b, wkvT, bkv, nullptr, kv, MROWS, 128, EE, 0, 0);

    // 5. RoPE on q (in place, 0.125 folded)
    {
        int total_q = MROWS * HH * 32;
        rope_q_kernel<<<(total_q + 255) / 256, 256, 0, stream>>>(qbf, total_q);
    }
    // 6. kv -> kbf (roped) + vtb (V transposed)
    prep_kv_kernel<<<dim3(SS / 64, BB), 256, 0, stream>>>(kv, kbf, vtb);

    // 7. attention -> ao [bf16]
    attn_mfma_kernel<<<dim3(SS / 128, HH, BB), 256, 0, stream>>>(qbf, kbf, vtb, ao);

    // 8. x2 = ao @ wo + bo + x  [fp32]
    gemm_bf16_kernel<<<dim3(EE / GN, MROWS / GM), 256, 0, stream>>>(
        ao, woT, bo, x, x2, MROWS, EE, EE, 1, 0);

    // 9. h2 = rmsnorm(x2, g2)
    rmsnorm_kernel<<<MROWS, 256, 0, stream>>>(x2, g2, h2b, EE);

    // 10. FFN weight transposes (reuse dead qbf slot + wuT region)
    transpose_cast_kernel<<<dim3(FFF / 32, EE / 32), 256, 0, stream>>>(wg, wgT, EE, FFF);
    transpose_cast_kernel<<<dim3(FFF / 32, EE / 32), 256, 0, stream>>>(wu, wuT, EE, FFF);

    // 11. gg = gelu(h2 @ wg + bg)  [bf16]
    gemm_bf16_kernel<<<dim3(FFF / GN, MROWS / GM), 256, 0, stream>>>(
        h2b, wgT, bg, nullptr, gg, MROWS, FFF, EE, 2, 1);

    // 12. gg = (h2 @ wu + bu) * gg  [bf16]
    gemm_bf16_kernel<<<dim3(FFF / GN, MROWS / GM), 256, 0, stream>>>(
        h2b, wuT, bu, gg, gg, MROWS, FFF, EE, 3, 1);

    // 13. wd transpose, then out = gg @ wd + bd + x2  [fp32]
    transpose_cast_kernel<<<dim3(EE / 32, FFF / 32), 256, 0, stream>>>(wd, wdT, FFF, EE);
    gemm_bf16_kernel<<<dim3(EE / GN, MROWS / GM), 256, 0, stream>>>(
        gg, wdT, bd, x2, out, MROWS, EE, FFF, 1, 0);
}

// Round 7
// 511.925 us; speedup vs baseline: 1.2989x; 1.2989x over previous
//
#include <hip/hip_runtime.h>
#include <hip/hip_bf16.h>
#include <math.h>

// Problem constants
#define BB 2
#define SS 2048
#define EE 1024
#define HH 16
#define HD 64
#define FFF 4096
#define MROWS (BB * SS)        // 4096
#define EPS_F 1.1920929e-7f
#define NQKV 1152              // 1024 q + 64 k + 64 v

typedef __hip_bfloat16 bf16;
typedef __attribute__((ext_vector_type(8))) short short8;
typedef __attribute__((ext_vector_type(4))) short short4v;
typedef __attribute__((ext_vector_type(4))) float floatx4;

typedef const __attribute__((address_space(1))) void* gas_t;
typedef __attribute__((address_space(3))) void* las_t;

// ---------------------------------------------------------------------------
// RMSNorm: fp32 in, bf16 out
// ---------------------------------------------------------------------------
__global__ __launch_bounds__(256) void rmsnorm_kernel(const float* __restrict__ x,
                                                      const float* __restrict__ g,
                                                      bf16* __restrict__ out,
                                                      int cols) {
    int row = blockIdx.x;
    const float* xr = x + (size_t)row * cols;
    float ss = 0.0f;
    for (int c = threadIdx.x; c < cols; c += 256) {
        float v = xr[c];
        ss += v * v;
    }
    for (int off = 32; off > 0; off >>= 1) ss += __shfl_xor(ss, off, 64);
    __shared__ float red[4];
    int wave = threadIdx.x >> 6;
    if ((threadIdx.x & 63) == 0) red[wave] = ss;
    __syncthreads();
    float tot = red[0] + red[1] + red[2] + red[3];
    float rs = rsqrtf(tot / (float)cols + EPS_F);
    bf16* orow = out + (size_t)row * cols;
    for (int c = threadIdx.x; c < cols; c += 256) {
        orow[c] = __float2bfloat16(xr[c] * rs * g[c]);
    }
}

// ---------------------------------------------------------------------------
// Cast + transpose: W (K x N, fp32) -> Wt (N x K, bf16). 32x32 LDS tiles.
// ---------------------------------------------------------------------------
__global__ __launch_bounds__(256) void transpose_cast_kernel(const float* __restrict__ W,
                                                             bf16* __restrict__ Wt,
                                                             int K, int N) {
    __shared__ float t[32][33];
    int n0 = blockIdx.x * 32, k0 = blockIdx.y * 32;
    int tx = threadIdx.x & 31, ty = threadIdx.x >> 5;   // ty 0..7
#pragma unroll
    for (int i = 0; i < 4; ++i) {
        int kk = ty + i * 8;
        t[kk][tx] = W[(size_t)(k0 + kk) * N + n0 + tx];
    }
    __syncthreads();
#pragma unroll
    for (int i = 0; i < 4; ++i) {
        int nn = ty + i * 8;
        Wt[(size_t)(n0 + nn) * K + k0 + tx] = __float2bfloat16(t[tx][nn]);
    }
}

// pack [bq | bk | bv] -> bqkv (1152 floats)
__global__ __launch_bounds__(256) void pack_bqkv_kernel(const float* __restrict__ bq,
                                                        const float* __restrict__ bk,
                                                        const float* __restrict__ bv,
                                                        float* __restrict__ bqkv) {
    int t = blockIdx.x * 256 + threadIdx.x;
    if (t >= NQKV) return;
    float v;
    if (t < 1024)      v = bq[t];
    else if (t < 1088) v = bk[t - 1024];
    else               v = bv[t - 1088];
    bqkv[t] = v;
}

// ---------------------------------------------------------------------------
// Fused QKV GEMM: [q|k|v] = h1 @ [wq|wk|wv]^T + bqkv.
// 128x128 tiles, BK=64, global_load_lds staging. N = 1152.
// cols < 1024 -> qbf (bf16, stride 1024); cols >= 1024 -> kv (fp32, stride 128)
// ---------------------------------------------------------------------------
#define GK 64

__global__ __launch_bounds__(256) void gemm_qkv_kernel(
        const bf16* __restrict__ A, const bf16* __restrict__ Bt,
        const float* __restrict__ bias,
        bf16* __restrict__ qout, float* __restrict__ kvout, int K) {
    __shared__ short As[128 * GK];
    __shared__ short Bs[128 * GK];
    int tid = threadIdx.x;
    int wave = tid >> 6, lane = tid & 63;
    int wm = (wave >> 1) * 64, wn = (wave & 1) * 64;
    int row0 = blockIdx.y * 128, col0 = blockIdx.x * 128;
    int lr = lane & 15, lq = lane >> 4;

    int srow = wave * 32 + (lane >> 3);
    int scol = (lane & 7) * 8;
    const bf16* Abase = A + (size_t)(row0 + srow) * K + scol;
    const bf16* Bbase = Bt + (size_t)(col0 + srow) * K + scol;

    floatx4 acc[4][4];
#pragma unroll
    for (int mi = 0; mi < 4; ++mi)
#pragma unroll
        for (int ni = 0; ni < 4; ++ni)
            acc[mi][ni] = (floatx4){0.f, 0.f, 0.f, 0.f};

    for (int k0 = 0; k0 < K; k0 += GK) {
        __syncthreads();
#pragma unroll
        for (int c = 0; c < 4; ++c) {
            __builtin_amdgcn_global_load_lds(
                (gas_t)(Abase + (size_t)(c * 8) * K + k0),
                (las_t)&As[(wave * 32 + c * 8) * GK], 16, 0, 0);
            __builtin_amdgcn_global_load_lds(
                (gas_t)(Bbase + (size_t)(c * 8) * K + k0),
                (las_t)&Bs[(wave * 32 + c * 8) * GK], 16, 0, 0);
        }
        __syncthreads();
#pragma unroll
        for (int ks = 0; ks < GK; ks += 32) {
            short8 af[4], bfr[4];
#pragma unroll
            for (int mi = 0; mi < 4; ++mi)
                af[mi] = *(const short8*)&As[(wm + mi * 16 + lr) * GK + ks + lq * 8];
#pragma unroll
            for (int ni = 0; ni < 4; ++ni)
                bfr[ni] = *(const short8*)&Bs[(wn + ni * 16 + lr) * GK + ks + lq * 8];
#pragma unroll
            for (int mi = 0; mi < 4; ++mi)
#pragma unroll
                for (int ni = 0; ni < 4; ++ni)
                    acc[mi][ni] = __builtin_amdgcn_mfma_f32_16x16x32_bf16(
                        af[mi], bfr[ni], acc[mi][ni], 0, 0, 0);
        }
    }

#pragma unroll
    for (int mi = 0; mi < 4; ++mi) {
#pragma unroll
        for (int ni = 0; ni < 4; ++ni) {
            int gc = col0 + wn + ni * 16 + lr;
            float bv = bias[gc];
#pragma unroll
            for (int r = 0; r < 4; ++r) {
                int gr = row0 + wm + mi * 16 + lq * 4 + r;
                float c = acc[mi][ni][r] + bv;
                if (gc < 1024) qout[(size_t)gr * 1024 + gc] = __float2bfloat16(c);
                else           kvout[(size_t)gr * 128 + (gc - 1024)] = c;
            }
        }
    }
}

// ---------------------------------------------------------------------------
// GEMM 128x64 tiles (for N=1024 outputs: wo, wd): C = A@Bt^T + bias + aux.
// 4 waves, each 32 rows x 64 cols (mi=2, ni=4). fp32 out, fp32 aux residual.
// ---------------------------------------------------------------------------
__global__ __launch_bounds__(256) void gemm_n64_kernel(
        const bf16* __restrict__ A, const bf16* __restrict__ Bt,
        const float* __restrict__ bias, const float* __restrict__ aux,
        float* __restrict__ C, int M, int N, int K) {
    __shared__ short As[128 * GK];
    __shared__ short Bs[64 * GK];
    int tid = threadIdx.x;
    int wave = tid >> 6, lane = tid & 63;
    int wm = wave * 32;
    int row0 = blockIdx.y * 128, col0 = blockIdx.x * 64;
    int lr = lane & 15, lq = lane >> 4;

    int srow = (lane >> 3);
    int scol = (lane & 7) * 8;
    const bf16* Abase = A + (size_t)(row0 + wave * 32 + srow) * K + scol;
    const bf16* Bbase = Bt + (size_t)(col0 + wave * 16 + srow) * K + scol;

    floatx4 acc[2][4];
#pragma unroll
    for (int mi = 0; mi < 2; ++mi)
#pragma unroll
        for (int ni = 0; ni < 4; ++ni)
            acc[mi][ni] = (floatx4){0.f, 0.f, 0.f, 0.f};

    for (int k0 = 0; k0 < K; k0 += GK) {
        __syncthreads();
#pragma unroll
        for (int c = 0; c < 4; ++c)
            __builtin_amdgcn_global_load_lds(
                (gas_t)(Abase + (size_t)(c * 8) * K + k0),
                (las_t)&As[(wave * 32 + c * 8) * GK], 16, 0, 0);
#pragma unroll
        for (int c = 0; c < 2; ++c)
            __builtin_amdgcn_global_load_lds(
                (gas_t)(Bbase + (size_t)(c * 8) * K + k0),
                (las_t)&Bs[(wave * 16 + c * 8) * GK], 16, 0, 0);
        __syncthreads();
#pragma unroll
        for (int ks = 0; ks < GK; ks += 32) {
            short8 af[2], bfr[4];
#pragma unroll
            for (int mi = 0; mi < 2; ++mi)
                af[mi] = *(const short8*)&As[(wm + mi * 16 + lr) * GK + ks + lq * 8];
#pragma unroll
            for (int ni = 0; ni < 4; ++ni)
                bfr[ni] = *(const short8*)&Bs[(ni * 16 + lr) * GK + ks + lq * 8];
#pragma unroll
            for (int mi = 0; mi < 2; ++mi)
#pragma unroll
                for (int ni = 0; ni < 4; ++ni)
                    acc[mi][ni] = __builtin_amdgcn_mfma_f32_16x16x32_bf16(
                        af[mi], bfr[ni], acc[mi][ni], 0, 0, 0);
        }
    }

#pragma unroll
    for (int mi = 0; mi < 2; ++mi) {
#pragma unroll
        for (int ni = 0; ni < 4; ++ni) {
            int gc = col0 + ni * 16 + lr;
            float bv = bias[gc];
#pragma unroll
            for (int r = 0; r < 4; ++r) {
                int gr = row0 + wm + mi * 16 + lq * 4 + r;
                size_t idx = (size_t)gr * N + gc;
                C[idx] = acc[mi][ni][r] + bv + aux[idx];
            }
        }
    }
}

// ---------------------------------------------------------------------------
// Fused FFN GEMM: gg = gelu(h2@wgT^T + bg) * (h2@wuT^T + bu). 128x128 tiles,
// two B banks staged per k-step, two accumulator banks. bf16 out.
// ---------------------------------------------------------------------------
__global__ __launch_bounds__(256, 2) void gemm_ffn_kernel(
        const bf16* __restrict__ A, const bf16* __restrict__ Bg,
        const bf16* __restrict__ Bu, const float* __restrict__ biasg,
        const float* __restrict__ biasu, bf16* __restrict__ C, int K) {
    __shared__ short As[128 * GK];
    __shared__ short Gs[128 * GK];
    __shared__ short Us[128 * GK];
    int tid = threadIdx.x;
    int wave = tid >> 6, lane = tid & 63;
    int wm = (wave >> 1) * 64, wn = (wave & 1) * 64;
    int row0 = blockIdx.y * 128, col0 = blockIdx.x * 128;
    int lr = lane & 15, lq = lane >> 4;

    int srow = wave * 32 + (lane >> 3);
    int scol = (lane & 7) * 8;
    const bf16* Abase = A + (size_t)(row0 + srow) * K + scol;
    const bf16* Gbase = Bg + (size_t)(col0 + srow) * K + scol;
    const bf16* Ubase = Bu + (size_t)(col0 + srow) * K + scol;

    floatx4 ag[4][4], au[4][4];
#pragma unroll
    for (int mi = 0; mi < 4; ++mi)
#pragma unroll
        for (int ni = 0; ni < 4; ++ni) {
            ag[mi][ni] = (floatx4){0.f, 0.f, 0.f, 0.f};
            au[mi][ni] = (floatx4){0.f, 0.f, 0.f, 0.f};
        }

    for (int k0 = 0; k0 < K; k0 += GK) {
        __syncthreads();
#pragma unroll
        for (int c = 0; c < 4; ++c) {
            __builtin_amdgcn_global_load_lds(
                (gas_t)(Abase + (size_t)(c * 8) * K + k0),
                (las_t)&As[(wave * 32 + c * 8) * GK], 16, 0, 0);
            __builtin_amdgcn_global_load_lds(
                (gas_t)(Gbase + (size_t)(c * 8) * K + k0),
                (las_t)&Gs[(wave * 32 + c * 8) * GK], 16, 0, 0);
            __builtin_amdgcn_global_load_lds(
                (gas_t)(Ubase + (size_t)(c * 8) * K + k0),
                (las_t)&Us[(wave * 32 + c * 8) * GK], 16, 0, 0);
        }
        __syncthreads();
#pragma unroll
        for (int ks = 0; ks < GK; ks += 32) {
            short8 af[4], gf[4], uf[4];
#pragma unroll
            for (int mi = 0; mi < 4; ++mi)
                af[mi] = *(const short8*)&As[(wm + mi * 16 + lr) * GK + ks + lq * 8];
#pragma unroll
            for (int ni = 0; ni < 4; ++ni) {
                gf[ni] = *(const short8*)&Gs[(wn + ni * 16 + lr) * GK + ks + lq * 8];
                uf[ni] = *(const short8*)&Us[(wn + ni * 16 + lr) * GK + ks + lq * 8];
            }
#pragma unroll
            for (int mi = 0; mi < 4; ++mi)
#pragma unroll
                for (int ni = 0; ni < 4; ++ni) {
                    ag[mi][ni] = __builtin_amdgcn_mfma_f32_16x16x32_bf16(
                        af[mi], gf[ni], ag[mi][ni], 0, 0, 0);
                    au[mi][ni] = __builtin_amdgcn_mfma_f32_16x16x32_bf16(
                        af[mi], uf[ni], au[mi][ni], 0, 0, 0);
                }
        }
    }

#pragma unroll
    for (int mi = 0; mi < 4; ++mi) {
#pragma unroll
        for (int ni = 0; ni < 4; ++ni) {
            int gc = col0 + wn + ni * 16 + lr;
            float bg_ = biasg[gc], bu_ = biasu[gc];
#pragma unroll
            for (int r = 0; r < 4; ++r) {
                int gr = row0 + wm + mi * 16 + lq * 4 + r;
                float g = ag[mi][ni][r] + bg_;
                float u = au[mi][ni][r] + bu_;
                float v = 0.5f * g * (1.0f + erff(g * 0.70710678118654752f)) * u;
                C[(size_t)gr * FFF + gc] = __float2bfloat16(v);
            }
        }
    }
}

// ---------------------------------------------------------------------------
// RoPE on bf16 q, in place, 1/sqrt(HD) folded. pos = row % SS.
// ---------------------------------------------------------------------------
__global__ __launch_bounds__(256) void rope_q_kernel(bf16* __restrict__ t, int total) {
    int idx = blockIdx.x * 256 + threadIdx.x;
    if (idx >= total) return;
    int i = idx & 31;
    int h = (idx >> 5) % HH;
    int row = idx / (32 * HH);
    int s = row & (SS - 1);
    float inv = powf(10000.0f, -(float)i / 32.0f);
    float ang = (float)s * inv;
    float c = cosf(ang), sn = sinf(ang);
    size_t base = (size_t)row * (HH * HD) + h * 64 + i;
    float t1 = (float)t[base];
    float t2 = (float)t[base + 32];
    t[base]      = __float2bfloat16((t1 * c - t2 * sn) * 0.125f);
    t[base + 32] = __float2bfloat16((t1 * sn + t2 * c) * 0.125f);
}

// ---------------------------------------------------------------------------
// prep_kv: kv fp32 (MROWS,128) -> kbf bf16 (MROWS,64) roped,
//          vtb bf16 (BB,64,SS) = V transposed per batch.
// ---------------------------------------------------------------------------
__global__ __launch_bounds__(256) void prep_kv_kernel(const float* __restrict__ kv,
                                                      bf16* __restrict__ kbf,
                                                      bf16* __restrict__ vtb) {
    __shared__ float vt[64][65];
    int s0 = blockIdx.x * 64;
    int b  = blockIdx.y;
    int tid = threadIdx.x;

    for (int i = tid; i < 2048; i += 256) {
        int sl = i >> 5, ii = i & 31;
        int s = s0 + sl;
        size_t base = ((size_t)(b * SS + s)) * 128;
        float k1 = kv[base + ii], k2 = kv[base + ii + 32];
        float inv = powf(10000.0f, -(float)ii / 32.0f);
        float ang = (float)s * inv;
        float c = cosf(ang), sn = sinf(ang);
        size_t ob = ((size_t)(b * SS + s)) * 64;
        kbf[ob + ii]      = __float2bfloat16(k1 * c - k2 * sn);
        kbf[ob + ii + 32] = __float2bfloat16(k1 * sn + k2 * c);
    }

    for (int i = tid; i < 4096; i += 256) {
        int s = i >> 6, d = i & 63;
        vt[d][s] = kv[((size_t)(b * SS + s0 + s)) * 128 + 64 + d];
    }
    __syncthreads();
    for (int i = tid; i < 4096; i += 256) {
        int d = i >> 6, sl = i & 63;
        vtb[((size_t)(b * 64 + d)) * SS + s0 + sl] = __float2bfloat16(vt[d][sl]);
    }
}

// ---------------------------------------------------------------------------
// MFMA flash attention v4: fixed-shift softmax (p = exp(s - 6), exact after
// normalization; |s| <~ 5 by norm bound), no per-tile reductions, no rescale.
// grid (16, HH, BB); block = 4 waves; block x handles q-tiles x and 31-x.
// K/V fragments direct from global (L1/L2-resident).
// ---------------------------------------------------------------------------
#define PST 68
#define SM_SHIFT 6.0f

__global__ __launch_bounds__(256) void attn_mfma_kernel(
        const bf16* __restrict__ q, const bf16* __restrict__ kb,
        const bf16* __restrict__ vt, bf16* __restrict__ o) {
    __shared__ short Ps[4][16 * PST];

    int h = blockIdx.y, b = blockIdx.z;
    int tid = threadIdx.x, w = tid >> 6, lane = tid & 63;
    int lr = lane & 15, quad = lane >> 4;

    const bf16* kbB = kb + (size_t)b * SS * 64;
    const bf16* vtB = vt + (size_t)b * 64 * SS;

    for (int pass = 0; pass < 2; ++pass) {
        int qt = (pass == 0) ? (int)blockIdx.x : (SS / 64 - 1 - (int)blockIdx.x);
        int q0 = qt * 64;

        const bf16* qrow = q + ((size_t)(b * SS + q0 + w * 16 + lr)) * (HH * HD) + h * HD;
        short8 qf0 = *(const short8*)(qrow + quad * 8);
        short8 qf1 = *(const short8*)(qrow + 32 + quad * 8);

        floatx4 O[4];
#pragma unroll
        for (int ni = 0; ni < 4; ++ni) O[ni] = (floatx4){0.f, 0.f, 0.f, 0.f};
        float lrow[4] = {0.f, 0.f, 0.f, 0.f};

        for (int t = 0; t <= qt; ++t) {
            int j0 = t * 64;

            // S = Q @ K^T
            floatx4 S[4];
#pragma unroll
            for (int ni = 0; ni < 4; ++ni) S[ni] = (floatx4){0.f, 0.f, 0.f, 0.f};
#pragma unroll
            for (int ni = 0; ni < 4; ++ni) {
                const bf16* kr = kbB + (size_t)(j0 + ni * 16 + lr) * 64 + quad * 8;
                short8 b0 = *(const short8*)(kr);
                short8 b1 = *(const short8*)(kr + 32);
                S[ni] = __builtin_amdgcn_mfma_f32_16x16x32_bf16(qf0, b0, S[ni], 0, 0, 0);
                S[ni] = __builtin_amdgcn_mfma_f32_16x16x32_bf16(qf1, b1, S[ni], 0, 0, 0);
            }

            // causal mask on diagonal tile
            if (t == qt) {
                int rowg = q0 + w * 16 + quad * 4;
#pragma unroll
                for (int ni = 0; ni < 4; ++ni) {
                    int colg = j0 + ni * 16 + lr;
#pragma unroll
                    for (int r = 0; r < 4; ++r)
                        if (colg > rowg + r) S[ni][r] = -3.0e38f;
                }
            }

            // fixed-shift exp; accumulate per-lane row sums (no cross-lane ops)
#pragma unroll
            for (int ni = 0; ni < 4; ++ni)
#pragma unroll
                for (int r = 0; r < 4; ++r)
                    S[ni][r] = __expf(S[ni][r] - SM_SHIFT);
#pragma unroll
            for (int r = 0; r < 4; ++r)
                lrow[r] += S[0][r] + S[1][r] + S[2][r] + S[3][r];

            // pack P (bf16) to wave-private LDS in C-layout
#pragma unroll
            for (int ni = 0; ni < 4; ++ni)
#pragma unroll
                for (int r = 0; r < 4; ++r) {
                    bf16 pb = __float2bfloat16(S[ni][r]);
                    Ps[w][(quad * 4 + r) * PST + ni * 16 + lr] = *(short*)&pb;
                }
            short4v a0 = *(const short4v*)&Ps[w][lr * PST + quad * 8];
            short4v a1 = *(const short4v*)&Ps[w][lr * PST + quad * 8 + 4];
            short4v a2 = *(const short4v*)&Ps[w][lr * PST + 32 + quad * 8];
            short4v a3 = *(const short4v*)&Ps[w][lr * PST + 32 + quad * 8 + 4];
            short8 p0 = __builtin_shufflevector(a0, a1, 0, 1, 2, 3, 4, 5, 6, 7);
            short8 p1 = __builtin_shufflevector(a2, a3, 0, 1, 2, 3, 4, 5, 6, 7);

            // O += P @ V
#pragma unroll
            for (int ni = 0; ni < 4; ++ni) {
                const bf16* vr = vtB + (size_t)(ni * 16 + lr) * SS + j0 + quad * 8;
                short8 v0 = *(const short8*)(vr);
                short8 v1 = *(const short8*)(vr + 32);
                O[ni] = __builtin_amdgcn_mfma_f32_16x16x32_bf16(p0, v0, O[ni], 0, 0, 0);
                O[ni] = __builtin_amdgcn_mfma_f32_16x16x32_bf16(p1, v1, O[ni], 0, 0, 0);
            }
        }

        // deferred row-sum reduction over the quad's 16 lanes (once per tile)
#pragma unroll
        for (int r = 0; r < 4; ++r) {
            float l = lrow[r];
            for (int off = 1; off < 16; off <<= 1) l += __shfl_xor(l, off, 64);
            lrow[r] = l;
        }

#pragma unroll
        for (int ni = 0; ni < 4; ++ni) {
            int gc = h * 64 + ni * 16 + lr;
#pragma unroll
            for (int r = 0; r < 4; ++r) {
                int gr = b * SS + q0 + w * 16 + quad * 4 + r;
                o[(size_t)gr * (HH * HD) + gc] = __float2bfloat16(O[ni][r] / lrow[r]);
            }
        }
    }
}

// ---------------------------------------------------------------------------
// Launch. Workspace (byte offsets, ~87 MB):
//   qbf @0 (8 MB, dead after attn; wgT reuses @0) | wuT @8M
//   x2 @16M (fp32 16 MB, alive to end) | h1b/h2b @32M (8 MB)
//   kv @40M (fp32 2 MB) | ao @42M (8 MB, dead after wo; wdT reuses)
//   gg @50M (32 MB; kbf/vtb live in its head pre-FFN)
//   wqkvT @82M (2.25 MB) | bqkv @84.5M | woT @85M (2 MB)
// ---------------------------------------------------------------------------
#define MB (1024ull * 1024ull)

extern "C" void kernel_launch(void* const* d_in, const int* in_sizes, int n_in,
                              void* d_out, int out_size, void* d_ws, size_t ws_size,
                              hipStream_t stream) {
    const float* x  = (const float*)d_in[0];
    const float* wq = (const float*)d_in[1];
    const float* bq = (const float*)d_in[2];
    const float* wk = (const float*)d_in[3];
    const float* bk = (const float*)d_in[4];
    const float* wv = (const float*)d_in[5];
    const float* bv = (const float*)d_in[6];
    const float* wo = (const float*)d_in[7];
    const float* bo = (const float*)d_in[8];
    const float* wg = (const float*)d_in[9];
    const float* bg = (const float*)d_in[10];
    const float* wu = (const float*)d_in[11];
    const float* bu = (const float*)d_in[12];
    const float* wd = (const float*)d_in[13];
    const float* bd = (const float*)d_in[14];
    const float* g1 = (const float*)d_in[15];
    const float* g2 = (const float*)d_in[16];
    float* out = (float*)d_out;

    char* ws = (char*)d_ws;
    bf16*  qbf   = (bf16*)(ws);
    bf16*  wuT   = (bf16*)(ws + 8 * MB);
    float* x2    = (float*)(ws + 16 * MB);
    bf16*  h1b   = (bf16*)(ws + 32 * MB);
    float* kv    = (float*)(ws + 40 * MB);
    bf16*  ao    = (bf16*)(ws + 42 * MB);
    bf16*  gg    = (bf16*)(ws + 50 * MB);
    bf16*  kbf   = (bf16*)(ws + 50 * MB);              // over gg head (dead by FFN)
    bf16*  vtb   = (bf16*)(ws + 50 * MB + 512 * 1024);
    bf16*  wqkvT = (bf16*)(ws + 82 * MB);              // 1152 x 1024 bf16
    float* bqkv  = (float*)(ws + 84 * MB + 512 * 1024);
    bf16*  woT   = (bf16*)(ws + 85 * MB);
    bf16*  wgT   = (bf16*)(ws);                        // over qbf (dead after attn)
    bf16*  wdT   = (bf16*)(ws + 42 * MB);              // over ao (dead after wo GEMM)
    bf16*  h2b   = h1b;

    // 1. h1 = rmsnorm(x, g1)
    rmsnorm_kernel<<<MROWS, 256, 0, stream>>>(x, g1, h1b, EE);

    // 2. weight transposes for attention block (wq|wk|wv packed rows)
    transpose_cast_kernel<<<dim3(EE / 32, EE / 32), 256, 0, stream>>>(wq, wqkvT, EE, EE);
    transpose_cast_kernel<<<dim3(HD / 32, EE / 32), 256, 0, stream>>>(wk, wqkvT + (size_t)1024 * EE, EE, HD);
    transpose_cast_kernel<<<dim3(HD / 32, EE / 32), 256, 0, stream>>>(wv, wqkvT + (size_t)1088 * EE, EE, HD);
    pack_bqkv_kernel<<<(NQKV + 255) / 256, 256, 0, stream>>>(bq, bk, bv, bqkv);
    transpose_cast_kernel<<<dim3(EE / 32, EE / 32), 256, 0, stream>>>(wo, woT, EE, EE);

    // 3. fused QKV projection
    gemm_qkv_kernel<<<dim3(NQKV / 128, MROWS / 128), 256, 0, stream>>>(
        h1b, wqkvT, bqkv, qbf, kv, EE);

    // 4. RoPE on q (in place, 0.125 folded); kv -> kbf (roped) + vtb
    {
        int total_q = MROWS * HH * 32;
        rope_q_kernel<<<(total_q + 255) / 256, 256, 0, stream>>>(qbf, total_q);
    }
    prep_kv_kernel<<<dim3(SS / 64, BB), 256, 0, stream>>>(kv, kbf, vtb);

    // 5. attention -> ao [bf16]
    attn_mfma_kernel<<<dim3(SS / 128, HH, BB), 256, 0, stream>>>(qbf, kbf, vtb, ao);

    // 6. x2 = ao @ wo + bo + x  [fp32]
    gemm_n64_kernel<<<dim3(EE / 64, MROWS / 128), 256, 0, stream>>>(
        ao, woT, bo, x, x2, MROWS, EE, EE);

    // 7. h2 = rmsnorm(x2, g2)
    rmsnorm_kernel<<<MROWS, 256, 0, stream>>>(x2, g2, h2b, EE);

    // 8. FFN weight transposes (reuse dead qbf slot + wuT region)
    transpose_cast_kernel<<<dim3(FFF / 32, EE / 32), 256, 0, stream>>>(wg, wgT, EE, FFF);
    transpose_cast_kernel<<<dim3(FFF / 32, EE / 32), 256, 0, stream>>>(wu, wuT, EE, FFF);

    // 9. gg = gelu(h2@wg+bg) * (h2@wu+bu)  [fused, bf16]
    gemm_ffn_kernel<<<dim3(FFF / 128, MROWS / 128), 256, 0, stream>>>(
        h2b, wgT, wuT, bg, bu, gg, EE);

    // 10. wd transpose, then out = gg @ wd + bd + x2  [fp32]
    transpose_cast_kernel<<<dim3(EE / 32, FFF / 32), 256, 0, stream>>>(wd, wdT, FFF, EE);
    gemm_n64_kernel<<<dim3(EE / 64, MROWS / 128), 256, 0, stream>>>(
        gg, wdT, bd, x2, out, MROWS, EE, FFF);
}